// Round 1
// baseline (2584.100 us; speedup 1.0000x reference)
//
#include <hip/hip_runtime.h>
#include <stdint.h>

// Show-Attend-Tell forward, MI355X. B=128, P=196, E=2048, H=512, V=10000, T=20.
// Strategy: bf16 MFMA (16x16x32) for all GEMMs (threshold = 2% of max -> safe),
// f32 state (c, gates, softmax, context). emb0@Wih folded into constant cbias.

typedef unsigned short u16;
typedef unsigned int u32;
typedef __attribute__((ext_vector_type(8))) short bf16x8;
typedef __attribute__((ext_vector_type(4))) float f32x4;

__device__ __forceinline__ float bf2f(u16 u) { return __uint_as_float(((u32)u) << 16); }
__device__ __forceinline__ u16 f2bf(float f) {
  u32 x = __float_as_uint(f);
  u32 r = x + 0x7fffu + ((x >> 16) & 1u);
  return (u16)(r >> 16);
}
__device__ __forceinline__ float tanh_f(float x) {
  x = fminf(15.f, fmaxf(-15.f, x));
  float e = __expf(2.f * x);
  return 1.f - 2.f * __builtin_amdgcn_rcpf(e + 1.f);
}
__device__ __forceinline__ float sigm_f(float x) {
  x = fminf(30.f, fmaxf(-30.f, x));
  return __builtin_amdgcn_rcpf(1.f + __expf(-x));
}

// ---- conversion: f32 -> bf16, 8 elems/thread, exact cover -------------------
__global__ __launch_bounds__(256) void k_f32_to_bf16(const float* __restrict__ in,
                                                     u16* __restrict__ out) {
  size_t i = ((size_t)blockIdx.x * 256 + threadIdx.x) * 8;
  float4 v0 = *(const float4*)(in + i);
  float4 v1 = *(const float4*)(in + i + 4);
  union { u16 u[8]; uint4 v; } r;
  r.u[0] = f2bf(v0.x); r.u[1] = f2bf(v0.y); r.u[2] = f2bf(v0.z); r.u[3] = f2bf(v0.w);
  r.u[4] = f2bf(v1.x); r.u[5] = f2bf(v1.y); r.u[6] = f2bf(v1.z); r.u[7] = f2bf(v1.w);
  *(uint4*)(out + i) = r.v;
}

// ---- mean over P (196) of imgb -> avgb bf16 ---------------------------------
__global__ __launch_bounds__(256) void k_avg(const u16* __restrict__ imgb,
                                             u16* __restrict__ avgb) {
  int b = blockIdx.y;
  int c0 = blockIdx.x * 512 + threadIdx.x * 2;
  const u32* p0 = (const u32*)(imgb + (size_t)b * 196 * 2048 + c0);
  float s0 = 0.f, s1 = 0.f;
  for (int p = 0; p < 196; ++p) {
    u32 v = p0[(size_t)p * 1024];
    s0 += bf2f((u16)(v & 0xffff));
    s1 += bf2f((u16)(v >> 16));
  }
  const float inv = 1.f / 196.f;
  u32 o = ((u32)f2bf(s1 * inv) << 16) | (u32)f2bf(s0 * inv);
  *(u32*)(avgb + (size_t)b * 2048 + c0) = o;
}

// ---- transpose f32[R,C] -> bf16[Cpad, R] (zero-fill c>=C), out_ld given -----
__global__ __launch_bounds__(256) void k_transpose_bf16(const float* __restrict__ in,
                                                        int R, int C, int Cpad,
                                                        u16* __restrict__ out, int out_ld) {
  __shared__ float tile[32][33];
  int c0 = blockIdx.x * 32, r0 = blockIdx.y * 32;
  int tx = threadIdx.x, ty = threadIdx.y;  // (32, 8)
#pragma unroll
  for (int i = 0; i < 32; i += 8) {
    int r = r0 + ty + i, c = c0 + tx;
    tile[ty + i][tx] = (r < R && c < C) ? in[(size_t)r * C + c] : 0.f;
  }
  __syncthreads();
#pragma unroll
  for (int i = 0; i < 32; i += 8) {
    int c = c0 + ty + i, r = r0 + tx;
    if (c < Cpad && r < R) out[(size_t)c * out_ld + r] = f2bf(tile[tx][ty + i]);
  }
}

// ---- cbias[n] = sum_k emb[0,k]*Wih[k,n] + bih[n] + bhh[n] -------------------
__global__ __launch_bounds__(256) void k_cbias(const float* __restrict__ emb,
                                               const float* __restrict__ Wih,
                                               const float* __restrict__ bih,
                                               const float* __restrict__ bhh,
                                               float* __restrict__ cb) {
  __shared__ float e0[512];
  int tid = threadIdx.x;
  for (int i = tid; i < 512; i += 256) e0[i] = emb[i];
  __syncthreads();
  int n = blockIdx.x * 256 + tid;
  float s = bih[n] + bhh[n];
  for (int k = 0; k < 512; ++k) s += e0[k] * Wih[(size_t)k * 2048 + n];
  cb[n] = s;
}

// ---- generic 64x64 MFMA GEMM: C = A[M,K](bf16) * BT[N,K](bf16)^T + epilogue -
enum { EPI_WS = 0, EPI_TANH_H, EPI_TANH_C, EPI_F32, EPI_GATE, EPI_OUT };

template <int EPI>
__global__ __launch_bounds__(256) void k_gemm64(
    const u16* __restrict__ A, const u16* __restrict__ BT, int K, int Ntiles,
    const float* __restrict__ bias, float* __restrict__ outF, u16* __restrict__ outB,
    u16* __restrict__ outB2, const float* __restrict__ ctx, long out_ld, int ncap) {
  __shared__ __align__(16) u16 Asm[64 * 72];  // +8 pad: conflict-free b128 r/w
  __shared__ __align__(16) u16 Bsm[64 * 72];
  int bid = blockIdx.x;
  int mt = bid / Ntiles, nt = bid % Ntiles;
  long m0 = (long)mt * 64, n0 = (long)nt * 64;
  int tid = threadIdx.x, lane = tid & 63, w = tid >> 6;
  int srow = tid >> 3, schk = tid & 7;
  f32x4 acc[4] = {};
  const u16* Ap0 = A + (m0 + srow) * K + schk * 8;
  const u16* Ap1 = A + (m0 + srow + 32) * K + schk * 8;
  const u16* Bp0 = BT + (n0 + srow) * K + schk * 8;
  const u16* Bp1 = BT + (n0 + srow + 32) * K + schk * 8;
  u16* Aw0 = Asm + srow * 72 + schk * 8;
  u16* Aw1 = Asm + (srow + 32) * 72 + schk * 8;
  u16* Bw0 = Bsm + srow * 72 + schk * 8;
  u16* Bw1 = Bsm + (srow + 32) * 72 + schk * 8;
  const u16* Ar = Asm + (w * 16 + (lane & 15)) * 72 + (lane >> 4) * 8;
  const u16* Br = Bsm + (lane & 15) * 72 + (lane >> 4) * 8;
  for (int k0 = 0; k0 < K; k0 += 64) {
    uint4 a0 = *(const uint4*)(Ap0 + k0);
    uint4 a1 = *(const uint4*)(Ap1 + k0);
    uint4 b0 = *(const uint4*)(Bp0 + k0);
    uint4 b1 = *(const uint4*)(Bp1 + k0);
    __syncthreads();
    *(uint4*)Aw0 = a0;
    *(uint4*)Aw1 = a1;
    *(uint4*)Bw0 = b0;
    *(uint4*)Bw1 = b1;
    __syncthreads();
#pragma unroll
    for (int kk = 0; kk < 2; ++kk) {
      bf16x8 af = *(const bf16x8*)(Ar + kk * 32);
#pragma unroll
      for (int sn = 0; sn < 4; ++sn) {
        bf16x8 bfr = *(const bf16x8*)(Br + sn * 16 * 72 + kk * 32);
        acc[sn] = __builtin_amdgcn_mfma_f32_16x16x32_bf16(af, bfr, acc[sn], 0, 0, 0);
      }
    }
  }
  int cb = lane & 15, rb = (lane >> 4) * 4;
#pragma unroll
  for (int sn = 0; sn < 4; ++sn) {
#pragma unroll
    for (int r = 0; r < 4; ++r) {
      long m = m0 + w * 16 + rb + r;
      long n = n0 + sn * 16 + cb;
      float v = acc[sn][r];
      if (EPI == EPI_WS) {
        outB[m * 512 + n] = f2bf(v + bias[n]);
      } else if (EPI == EPI_TANH_H) {
        u16 hv = f2bf(tanh_f(v + bias[n]));
        outB[m * 512 + n] = hv;
        outB2[m * 2560 + n] = hv;
      } else if (EPI == EPI_TANH_C) {
        outF[m * 512 + n] = tanh_f(v + bias[n]);
      } else if (EPI == EPI_F32) {
        outF[m * out_ld + n] = v + bias[n];
      } else if (EPI == EPI_GATE) {
        float g = sigm_f(v + bias[n]);
        outB[m * 2560 + n] = f2bf(g * ctx[m * 2048 + n]);
      } else {  // EPI_OUT
        if (n < ncap) outF[m * out_ld + n] = v + bias[n];
      }
    }
  }
}

// ---- attention: e[b,p] = sum_h tanh(Ws[b,p,h]+hU[b,h])*v[h]; softmax -> alpha
__global__ __launch_bounds__(512) void k_attn_e(const u16* __restrict__ Ws,
                                                const float* __restrict__ hU,
                                                const float* __restrict__ v_w,
                                                float* __restrict__ alpha_buf,
                                                float* __restrict__ alphas_out) {
  int b = blockIdx.x, tid = threadIdx.x, lane = tid & 63, w = tid >> 6;
  __shared__ float hU_s[512], v_s[512], e_s[200];
  hU_s[tid] = hU[b * 512 + tid];
  v_s[tid] = v_w[tid];
  __syncthreads();
  for (int p = w; p < 196; p += 8) {
    uint4 pk = *(const uint4*)(Ws + ((size_t)b * 196 + p) * 512 + lane * 8);
    const u16* u = (const u16*)&pk;
    float s = 0.f;
#pragma unroll
    for (int j = 0; j < 8; ++j) {
      int h = lane * 8 + j;
      s += tanh_f(bf2f(u[j]) + hU_s[h]) * v_s[h];
    }
#pragma unroll
    for (int off = 32; off; off >>= 1) s += __shfl_xor(s, off);
    if (lane == 0) e_s[p] = s;  // v_b cancels in softmax
  }
  __syncthreads();
  if (w == 0) {
    float mx = -1e30f;
    for (int q = lane; q < 196; q += 64) mx = fmaxf(mx, e_s[q]);
#pragma unroll
    for (int off = 32; off; off >>= 1) mx = fmaxf(mx, __shfl_xor(mx, off));
    float ssum = 0.f;
    for (int q = lane; q < 196; q += 64) {
      float ex = __expf(e_s[q] - mx);
      e_s[q] = ex;
      ssum += ex;
    }
#pragma unroll
    for (int off = 32; off; off >>= 1) ssum += __shfl_xor(ssum, off);
    float inv = 1.f / ssum;
    for (int q = lane; q < 196; q += 64) e_s[q] *= inv;
  }
  __syncthreads();
  if (tid < 196) {
    float a = e_s[tid];
    alpha_buf[b * 196 + tid] = a;
    alphas_out[(size_t)b * 3920 + tid] = a;  // alphas[b, t, p], stride_b = 20*196
  }
}

// ---- context[b,:] = sum_p alpha[b,p] * imgb[b,p,:] --------------------------
__global__ __launch_bounds__(512) void k_context(const float* __restrict__ alpha_buf,
                                                 const u16* __restrict__ imgb,
                                                 float* __restrict__ ctx) {
  int b = blockIdx.x >> 1, half = blockIdx.x & 1, tid = threadIdx.x;
  __shared__ float al[196];
  if (tid < 196) al[tid] = alpha_buf[b * 196 + tid];
  __syncthreads();
  int c0 = half * 1024 + tid * 2;
  const u32* base = (const u32*)(imgb + (size_t)b * 196 * 2048 + c0);
  float a0 = 0.f, a1 = 0.f;
#pragma unroll 4
  for (int p = 0; p < 196; ++p) {
    u32 v = base[(size_t)p * 1024];
    float ap = al[p];
    a0 += ap * bf2f((u16)(v & 0xffff));
    a1 += ap * bf2f((u16)(v >> 16));
  }
  ctx[(size_t)b * 2048 + c0] = a0;
  ctx[(size_t)b * 2048 + c0 + 1] = a1;
}

// ---- LSTM cell elementwise --------------------------------------------------
__global__ __launch_bounds__(256) void k_lstm_cell(const float* __restrict__ gates,
                                                   float* __restrict__ c,
                                                   u16* __restrict__ hb,
                                                   u16* __restrict__ Abuf) {
  int idx = blockIdx.x * 256 + threadIdx.x;  // 128*512
  int b = idx >> 9, n = idx & 511;
  const float* g = gates + (size_t)b * 2048;
  float i = sigm_f(g[n]);
  float f = sigm_f(g[512 + n]);
  float gg = tanh_f(g[1024 + n]);
  float o = sigm_f(g[1536 + n]);
  float cn = f * c[idx] + i * gg;
  float h = o * tanh_f(cn);
  c[idx] = cn;
  u16 hv = f2bf(h);
  hb[idx] = hv;
  Abuf[(size_t)b * 2560 + 2048 + n] = hv;
}

extern "C" void kernel_launch(void* const* d_in, const int* in_sizes, int n_in,
                              void* d_out, int out_size, void* d_ws, size_t ws_size,
                              hipStream_t stream) {
  const float* img = (const float*)d_in[0];
  // d_in[1] captions: only defines static T=20; d_in[7] v_b: cancels in softmax
  const float* U_w = (const float*)d_in[2];
  const float* U_b = (const float*)d_in[3];
  const float* W_w = (const float*)d_in[4];
  const float* W_b = (const float*)d_in[5];
  const float* v_w = (const float*)d_in[6];
  const float* ih_w = (const float*)d_in[8];
  const float* ih_b = (const float*)d_in[9];
  const float* ic_w = (const float*)d_in[10];
  const float* ic_b = (const float*)d_in[11];
  const float* fb_w = (const float*)d_in[12];
  const float* fb_b = (const float*)d_in[13];
  const float* out_w = (const float*)d_in[14];
  const float* out_b = (const float*)d_in[15];
  const float* emb = (const float*)d_in[16];
  const float* Wih = (const float*)d_in[17];
  const float* Whh = (const float*)d_in[18];
  const float* bih = (const float*)d_in[19];
  const float* bhh = (const float*)d_in[20];
  float* preds = (float*)d_out;                    // [128,20,10000]
  float* alphas = (float*)d_out + 25600000;        // [128,20,196]

  char* ws = (char*)d_ws;
  size_t off = 0;
  auto alloc = [&](size_t bytes) {
    void* p = ws + off;
    off = (off + bytes + 255) & ~(size_t)255;
    return p;
  };
  u16* imgb = (u16*)alloc((size_t)128 * 196 * 2048 * 2);   // 102.8 MB
  u16* avgb = (u16*)alloc((size_t)128 * 2048 * 2);
  u16* WsB = (u16*)alloc((size_t)128 * 196 * 512 * 2);     // 25.7 MB
  u16* WwT = (u16*)alloc((size_t)512 * 2048 * 2);
  u16* UwT = (u16*)alloc((size_t)512 * 512 * 2);
  u16* ihT = (u16*)alloc((size_t)512 * 2048 * 2);
  u16* icT = (u16*)alloc((size_t)512 * 2048 * 2);
  u16* fbT = (u16*)alloc((size_t)2048 * 512 * 2);
  u16* WcT = (u16*)alloc((size_t)2048 * 2560 * 2);         // 10.5 MB
  u16* owT = (u16*)alloc((size_t)10048 * 512 * 2);         // 10.3 MB (zero-pad)
  float* cbias = (float*)alloc(2048 * 4);
  u16* hb = (u16*)alloc((size_t)128 * 512 * 2);
  float* cbuf = (float*)alloc((size_t)128 * 512 * 4);
  float* hU = (float*)alloc((size_t)128 * 512 * 4);
  float* albuf = (float*)alloc((size_t)128 * 196 * 4);
  float* ctx = (float*)alloc((size_t)128 * 2048 * 4);
  u16* Abuf = (u16*)alloc((size_t)128 * 2560 * 2);
  float* gates = (float*)alloc((size_t)128 * 2048 * 4);
  if (off > ws_size) return;  // workspace too small -> fail loudly via absmax
  (void)in_sizes; (void)n_in; (void)out_size;

  dim3 tb(32, 8);
  // --- one-time precompute (replayed every call; deterministic) ---
  k_f32_to_bf16<<<25088, 256, 0, stream>>>(img, imgb);
  k_avg<<<dim3(4, 128), 256, 0, stream>>>(imgb, avgb);
  k_transpose_bf16<<<dim3(16, 64), tb, 0, stream>>>(W_w, 2048, 512, 512, WwT, 2048);
  k_transpose_bf16<<<dim3(16, 16), tb, 0, stream>>>(U_w, 512, 512, 512, UwT, 512);
  k_transpose_bf16<<<dim3(16, 64), tb, 0, stream>>>(ih_w, 2048, 512, 512, ihT, 2048);
  k_transpose_bf16<<<dim3(16, 64), tb, 0, stream>>>(ic_w, 2048, 512, 512, icT, 2048);
  k_transpose_bf16<<<dim3(64, 16), tb, 0, stream>>>(fb_w, 512, 2048, 2048, fbT, 512);
  k_transpose_bf16<<<dim3(314, 16), tb, 0, stream>>>(out_w, 512, 10000, 10048, owT, 512);
  k_transpose_bf16<<<dim3(64, 64), tb, 0, stream>>>(Wih + 512 * 2048, 2048, 2048, 2048, WcT, 2560);
  k_transpose_bf16<<<dim3(64, 16), tb, 0, stream>>>(Whh, 512, 2048, 2048, WcT + 2048, 2560);
  k_cbias<<<8, 256, 0, stream>>>(emb, Wih, bih, bhh, cbias);
  // W_s = img @ W_w + W_b  (stored bf16 [25088, 512])
  k_gemm64<EPI_WS><<<392 * 8, 256, 0, stream>>>(imgb, WwT, 2048, 8, W_b, nullptr, WsB,
                                                nullptr, nullptr, 0L, 0);
  // h0 / c0 from mean-pooled features
  k_gemm64<EPI_TANH_H><<<16, 256, 0, stream>>>(avgb, ihT, 2048, 8, ih_b, nullptr, hb,
                                               Abuf + 2048, nullptr, 0L, 0);
  k_gemm64<EPI_TANH_C><<<16, 256, 0, stream>>>(avgb, icT, 2048, 8, ic_b, cbuf, nullptr,
                                               nullptr, nullptr, 0L, 0);

  for (int t = 0; t < 20; ++t) {
    // hU = h @ U_w + U_b
    k_gemm64<EPI_F32><<<16, 256, 0, stream>>>(hb, UwT, 512, 8, U_b, hU, nullptr,
                                              nullptr, nullptr, 512L, 0);
    k_attn_e<<<128, 512, 0, stream>>>(WsB, hU, v_w, albuf, alphas + (size_t)t * 196);
    k_context<<<256, 512, 0, stream>>>(albuf, imgb, ctx);
    // xc = sigmoid(h@f_beta + b) * context -> Abuf[:, 0:2048]
    k_gemm64<EPI_GATE><<<64, 256, 0, stream>>>(hb, fbT, 512, 32, fb_b, nullptr, Abuf,
                                               nullptr, ctx, 0L, 0);
    // gates = [xc, h] @ [Wih_ctx; Whh] + cbias
    k_gemm64<EPI_F32><<<64, 256, 0, stream>>>(Abuf, WcT, 2560, 32, cbias, gates,
                                              nullptr, nullptr, nullptr, 2048L, 0);
    k_lstm_cell<<<256, 256, 0, stream>>>(gates, cbuf, hb, Abuf);
    // preds[:, t, :] = h_new @ out_w + out_b
    k_gemm64<EPI_OUT><<<2 * 157, 256, 0, stream>>>(hb, owT, 512, 157, out_b,
                                                   preds + (size_t)t * 10000, nullptr,
                                                   nullptr, nullptr, 200000L, 10000);
  }
}